// Round 1
// baseline (7887.823 us; speedup 1.0000x reference)
//
#include <hip/hip_runtime.h>

// ---------------------------------------------------------------------------
// Nystrom attention, fp32 baseline.
// b=2, h=8, n=8192, d=64, m=256 landmarks, l=32, conv kernel 33 (pad 16).
// bh = b*h = 16 flattened batch-head index throughout.
// ---------------------------------------------------------------------------

#define N_SEQ 8192
#define NBH   16
#define MLAND 256
#define DHEAD 64

// ---------------------------------------------------------------------------
// 1) landmark means: ql/kl[bh,mi,d] = mean over 32 rows of q/k
//    grid (NBH*MLAND, 2), block 64
// ---------------------------------------------------------------------------
__global__ __launch_bounds__(64) void k_landmarks(
    const float* __restrict__ q, const float* __restrict__ k,
    float* __restrict__ ql, float* __restrict__ kl)
{
    int mi = blockIdx.x & 255;
    int bh = blockIdx.x >> 8;
    const float* src = blockIdx.y ? k : q;
    float*       dst = blockIdx.y ? kl : ql;
    int t = threadIdx.x;
    const float* s = src + ((size_t)bh * N_SEQ + (size_t)mi * 32) * DHEAD;
    float acc = 0.f;
    #pragma unroll
    for (int j = 0; j < 32; ++j) acc += s[j * DHEAD + t];
    dst[((size_t)bh * MLAND + mi) * DHEAD + t] = acc * (1.f / 32.f);
}

// ---------------------------------------------------------------------------
// 2) attn2 = softmax(ql @ kl^T) rowwise. One block per (bh,row), 256 threads.
// ---------------------------------------------------------------------------
__global__ __launch_bounds__(256) void k_sim2_softmax(
    const float* __restrict__ ql, const float* __restrict__ kl,
    float* __restrict__ attn2)
{
    int bh = blockIdx.x >> 8;
    int i  = blockIdx.x & 255;
    int t  = threadIdx.x;           // landmark j
    __shared__ float qrow[DHEAD];
    __shared__ float wred[8];
    if (t < DHEAD) qrow[t] = ql[((size_t)bh * MLAND + i) * DHEAD + t];
    __syncthreads();
    const float* krow = kl + ((size_t)bh * MLAND + t) * DHEAD;
    float s = 0.f;
    #pragma unroll
    for (int kk = 0; kk < DHEAD; kk += 4) {
        float4 k4 = *(const float4*)(krow + kk);
        s += qrow[kk] * k4.x + qrow[kk + 1] * k4.y + qrow[kk + 2] * k4.z + qrow[kk + 3] * k4.w;
    }
    // block max
    float m = s;
    #pragma unroll
    for (int o = 32; o > 0; o >>= 1) m = fmaxf(m, __shfl_xor(m, o, 64));
    int wave = t >> 6, lane = t & 63;
    if (lane == 0) wred[wave] = m;
    __syncthreads();
    float bm = fmaxf(fmaxf(wred[0], wred[1]), fmaxf(wred[2], wred[3]));
    float e = __expf(s - bm);
    float sum = e;
    #pragma unroll
    for (int o = 32; o > 0; o >>= 1) sum += __shfl_xor(sum, o, 64);
    if (lane == 0) wred[4 + wave] = sum;
    __syncthreads();
    float bs = wred[4] + wred[5] + wred[6] + wred[7];
    attn2[((size_t)bh * MLAND + i) * MLAND + t] = e / bs;
}

// ---------------------------------------------------------------------------
// 3a) global max of row-sums and col-sums of attn2 (all positive).
//     scl[0] = max row-sum (ref "col"), scl[1] = max col-sum (ref "row").
//     One block per bh; atomicMax via uint bits (valid: values >= 0).
// ---------------------------------------------------------------------------
__global__ __launch_bounds__(256) void k_scale_reduce(
    const float* __restrict__ x, float* __restrict__ scl)
{
    int bh = blockIdx.x, t = threadIdx.x;
    const float* xb = x + (size_t)bh * MLAND * MLAND;
    float colsum = 0.f, rowsum = 0.f;
    for (int i = 0; i < MLAND; ++i) colsum += xb[(size_t)i * MLAND + t];  // column t
    for (int j = 0; j < MLAND; ++j) rowsum += xb[(size_t)t * MLAND + j];  // row t
    __shared__ float red[256];
    red[t] = rowsum;
    __syncthreads();
    for (int o = 128; o > 0; o >>= 1) {
        if (t < o) red[t] = fmaxf(red[t], red[t + o]);
        __syncthreads();
    }
    if (t == 0) atomicMax((unsigned int*)&scl[0], __float_as_uint(red[0]));
    __syncthreads();
    red[t] = colsum;
    __syncthreads();
    for (int o = 128; o > 0; o >>= 1) {
        if (t < o) red[t] = fmaxf(red[t], red[t + o]);
        __syncthreads();
    }
    if (t == 0) atomicMax((unsigned int*)&scl[1], __float_as_uint(red[0]));
}

// ---------------------------------------------------------------------------
// 3b) z0 = attn2^T / (scl[0]*scl[1]). 32x32 smem transpose tiles.
//     grid (8,8,16), block 256.
// ---------------------------------------------------------------------------
__global__ __launch_bounds__(256) void k_zinit(
    const float* __restrict__ x, float* __restrict__ z,
    const float* __restrict__ scl)
{
    __shared__ float tile[32][33];
    int bh = blockIdx.z;
    int i0 = blockIdx.y * 32, j0 = blockIdx.x * 32;
    int t = threadIdx.x;
    int lx = t & 31, ly = t >> 5;  // 32 x 8, 4 passes
    const float* xb = x + (size_t)bh * MLAND * MLAND;
    float*       zb = z + (size_t)bh * MLAND * MLAND;
    #pragma unroll
    for (int p = 0; p < 4; ++p)
        tile[ly + 8 * p][lx] = xb[(size_t)(i0 + ly + 8 * p) * MLAND + j0 + lx];
    __syncthreads();
    float inv = 1.0f / (scl[0] * scl[1]);
    #pragma unroll
    for (int p = 0; p < 4; ++p)
        zb[(size_t)(j0 + ly + 8 * p) * MLAND + i0 + lx] = tile[lx][ly + 8 * p] * inv;
}

// ---------------------------------------------------------------------------
// 4) batched C = outscale * (A @ (diag*I + bscale*B)); 64x64 tiles, K-chunks 16.
//    grid (N/64, M/64, NBH), block 256 (16x16 threads, 4x4 micro-tile).
// ---------------------------------------------------------------------------
__global__ __launch_bounds__(256) void k_bmm_affine(
    const float* __restrict__ A, const float* __restrict__ B, float* __restrict__ C,
    int M, int N, int K, float diag, float bscale, float outscale)
{
    __shared__ __align__(16) float As[16][68];  // [k][m], 68-stride: 16B-aligned rows
    __shared__ __align__(16) float Bs[16][68];  // [k][n]
    int bh = blockIdx.z;
    const float* Ab = A + (size_t)bh * M * K;
    const float* Bb = B + (size_t)bh * K * N;
    float*       Cb = C + (size_t)bh * M * N;
    int m0 = blockIdx.y * 64, n0 = blockIdx.x * 64;
    int t = threadIdx.x;
    int tx = t & 15, ty = t >> 4;
    float acc[4][4] = {};
    for (int k0 = 0; k0 < K; k0 += 16) {
        {   // stage A tile (transposed into [k][m])
            int mm = t >> 2, kk0 = (t & 3) * 4;
            float4 av = *(const float4*)&Ab[(size_t)(m0 + mm) * K + k0 + kk0];
            As[kk0 + 0][mm] = av.x; As[kk0 + 1][mm] = av.y;
            As[kk0 + 2][mm] = av.z; As[kk0 + 3][mm] = av.w;
        }
        {   // stage B tile with fused affine (diag*I + bscale*B)
            int kk = t >> 4, nn0 = (t & 15) * 4;
            float4 bv = *(const float4*)&Bb[(size_t)(k0 + kk) * N + n0 + nn0];
            float rr[4] = {bv.x, bv.y, bv.z, bv.w};
            #pragma unroll
            for (int o = 0; o < 4; ++o) {
                float val = bscale * rr[o];
                if (k0 + kk == n0 + nn0 + o) val += diag;
                Bs[kk][nn0 + o] = val;
            }
        }
        __syncthreads();
        #pragma unroll
        for (int kk = 0; kk < 16; ++kk) {
            float4 a4 = *(const float4*)&As[kk][ty * 4];
            float4 b4 = *(const float4*)&Bs[kk][tx * 4];
            float a[4] = {a4.x, a4.y, a4.z, a4.w};
            float b[4] = {b4.x, b4.y, b4.z, b4.w};
            #pragma unroll
            for (int i = 0; i < 4; ++i)
                #pragma unroll
                for (int j = 0; j < 4; ++j) acc[i][j] += a[i] * b[j];
        }
        __syncthreads();
    }
    #pragma unroll
    for (int i = 0; i < 4; ++i) {
        float4 cv = make_float4(acc[i][0] * outscale, acc[i][1] * outscale,
                                acc[i][2] * outscale, acc[i][3] * outscale);
        *(float4*)&Cb[(size_t)(m0 + ty * 4 + i) * N + n0 + tx * 4] = cv;
    }
}

// ---------------------------------------------------------------------------
// 5) kv = softmax(ql @ k^T) @ v, fused online-softmax (flash) over n.
//    8 landmarks per block, 64-row K/V chunks. grid (32, NBH), block 256.
// ---------------------------------------------------------------------------
__global__ __launch_bounds__(256) void k_attn3_kv(
    const float* __restrict__ ql, const float* __restrict__ k,
    const float* __restrict__ v, float* __restrict__ kv)
{
    int bh = blockIdx.y;
    int g0 = blockIdx.x * 8;
    int t = threadIdx.x;
    __shared__ float qs[8][65];
    __shared__ float kc[64][65];
    __shared__ __align__(16) float vc[64][64];
    __shared__ float pp[8][64];
    __shared__ float Mg[8], Sg[8], nM[8], al[8];

    for (int idx = t; idx < 8 * DHEAD; idx += 256) {
        int g = idx >> 6, col = idx & 63;
        qs[g][col] = ql[((size_t)bh * MLAND + g0 + g) * DHEAD + col];
    }
    if (t < 8) { Mg[t] = -1e30f; Sg[t] = 0.f; }
    float acc1 = 0.f, acc2 = 0.f;
    int gA = t >> 6, gB = gA + 4, d = t & 63;
    const float* kb = k + (size_t)bh * N_SEQ * DHEAD;
    const float* vb = v + (size_t)bh * N_SEQ * DHEAD;
    __syncthreads();

    for (int c0 = 0; c0 < N_SEQ; c0 += 64) {
        {   // stage K/V chunk
            int row = t >> 2, col0 = (t & 3) * 16;
            const float* srck = kb + (size_t)(c0 + row) * DHEAD + col0;
            const float* srcv = vb + (size_t)(c0 + row) * DHEAD + col0;
            #pragma unroll
            for (int o = 0; o < 16; o += 4) {
                float4 val = *(const float4*)(srck + o);
                kc[row][col0 + o + 0] = val.x; kc[row][col0 + o + 1] = val.y;
                kc[row][col0 + o + 2] = val.z; kc[row][col0 + o + 3] = val.w;
            }
            #pragma unroll
            for (int o = 0; o < 16; o += 4)
                *(float4*)&vc[row][col0 + o] = *(const float4*)(srcv + o);
        }
        __syncthreads();
        // scores: each thread 2 dots (g uniform per wave -> qs broadcast)
        #pragma unroll
        for (int half = 0; half < 2; ++half) {
            int g = (t >> 6) + half * 4;
            int j = t & 63;
            float s = 0.f;
            #pragma unroll 8
            for (int kk = 0; kk < DHEAD; ++kk) s += qs[g][kk] * kc[j][kk];
            pp[g][j] = s;
        }
        __syncthreads();
        {   // per-g chunk max + rescale factor
            int g = t >> 5, cc = t & 31;
            float mv = fmaxf(pp[g][cc], pp[g][cc + 32]);
            #pragma unroll
            for (int o = 16; o > 0; o >>= 1) mv = fmaxf(mv, __shfl_xor(mv, o, 32));
            if (cc == 0) {
                float nm = fmaxf(Mg[g], mv);
                nM[g] = nm;
                al[g] = __expf(Mg[g] - nm);
            }
        }
        __syncthreads();
        #pragma unroll
        for (int half = 0; half < 2; ++half) {
            int g = (t >> 6) + half * 4;
            int j = t & 63;
            pp[g][j] = __expf(pp[g][j] - nM[g]);
        }
        acc1 *= al[gA]; acc2 *= al[gB];
        __syncthreads();
        {   // per-g sum, state update
            int g = t >> 5, cc = t & 31;
            float sv = pp[g][cc] + pp[g][cc + 32];
            #pragma unroll
            for (int o = 16; o > 0; o >>= 1) sv += __shfl_xor(sv, o, 32);
            if (cc == 0) { Sg[g] = Sg[g] * al[g] + sv; Mg[g] = nM[g]; }
        }
        // accumulate O
        #pragma unroll 8
        for (int j = 0; j < 64; ++j) {
            float vv = vc[j][d];
            acc1 += pp[gA][j] * vv;
            acc2 += pp[gB][j] * vv;
        }
        __syncthreads();
    }
    kv[((size_t)bh * MLAND + g0 + gA) * DHEAD + d] = acc1 / Sg[gA];
    kv[((size_t)bh * MLAND + g0 + gB) * DHEAD + d] = acc2 / Sg[gB];
}

// ---------------------------------------------------------------------------
// 6) out = softmax(q @ kl^T) @ W  + depthwise-conv33(v). 32 q-rows per block.
//    grid (256, NBH), block 256 (thread = (r = t>>3, c = t&7), 8 cols each).
// ---------------------------------------------------------------------------
__global__ __launch_bounds__(256) void k_attn1_out(
    const float* __restrict__ q, const float* __restrict__ kl,
    const float* __restrict__ W, const float* __restrict__ v,
    const float* __restrict__ cw, float* __restrict__ out)
{
    int bh = blockIdx.y;
    int r0 = blockIdx.x * 32;
    int h  = bh & 7;
    int t  = threadIdx.x;
    int r = t >> 3, c = t & 7;

    __shared__ float qt[32][65];     // q tile
    __shared__ float bt[64][65];     // kl / W / v chunk (reused)
    __shared__ float sS[32][257];    // scores -> exp(scores)
    __shared__ float rowsum[32];
    __shared__ float wgt[33];

    {   // stage q tile
        int row = t >> 3, col0 = (t & 7) * 8;
        const float* src = q + ((size_t)bh * N_SEQ + r0 + row) * DHEAD + col0;
        float4 a = *(const float4*)(src);
        float4 b = *(const float4*)(src + 4);
        qt[row][col0 + 0] = a.x; qt[row][col0 + 1] = a.y;
        qt[row][col0 + 2] = a.z; qt[row][col0 + 3] = a.w;
        qt[row][col0 + 4] = b.x; qt[row][col0 + 5] = b.y;
        qt[row][col0 + 6] = b.z; qt[row][col0 + 7] = b.w;
    }
    if (t < 33) wgt[t] = cw[h * 33 + t];

    // phase 1: scores s = q_tile @ kl^T (4 chunks of 64 landmarks)
    for (int mc = 0; mc < 4; ++mc) {
        {
            int row = t >> 2, col0 = (t & 3) * 16;
            const float* src = kl + ((size_t)bh * MLAND + mc * 64 + row) * DHEAD + col0;
            #pragma unroll
            for (int o = 0; o < 16; o += 4) {
                float4 val = *(const float4*)(src + o);
                bt[row][col0 + o + 0] = val.x; bt[row][col0 + o + 1] = val.y;
                bt[row][col0 + o + 2] = val.z; bt[row][col0 + o + 3] = val.w;
            }
        }
        __syncthreads();
        float dot[8] = {0, 0, 0, 0, 0, 0, 0, 0};
        #pragma unroll 8
        for (int kk = 0; kk < DHEAD; ++kk) {
            float qv = qt[r][kk];
            #pragma unroll
            for (int jo = 0; jo < 8; ++jo) dot[jo] += qv * bt[c * 8 + jo][kk];
        }
        #pragma unroll
        for (int jo = 0; jo < 8; ++jo) sS[r][mc * 64 + c * 8 + jo] = dot[jo];
        __syncthreads();
    }

    // phase 2: rowwise softmax (8 threads per row), keep unnormalized exp
    {
        float mv = -1e30f;
        for (int j = c; j < MLAND; j += 8) mv = fmaxf(mv, sS[r][j]);
        #pragma unroll
        for (int o = 4; o > 0; o >>= 1) mv = fmaxf(mv, __shfl_xor(mv, o, 8));
        float sum = 0.f;
        for (int j = c; j < MLAND; j += 8) {
            float e = __expf(sS[r][j] - mv);
            sS[r][j] = e;
            sum += e;
        }
        #pragma unroll
        for (int o = 4; o > 0; o >>= 1) sum += __shfl_xor(sum, o, 8);
        if (c == 0) rowsum[r] = sum;
    }
    __syncthreads();

    // phase 3: out_tile = expS @ W (4 chunks of 64 W-rows)
    float acc[8] = {0, 0, 0, 0, 0, 0, 0, 0};
    for (int mc = 0; mc < 4; ++mc) {
        {
            int row = t >> 2, col0 = (t & 3) * 16;
            const float* src = W + ((size_t)bh * MLAND + mc * 64 + row) * DHEAD + col0;
            #pragma unroll
            for (int o = 0; o < 16; o += 4) {
                float4 val = *(const float4*)(src + o);
                bt[row][col0 + o + 0] = val.x; bt[row][col0 + o + 1] = val.y;
                bt[row][col0 + o + 2] = val.z; bt[row][col0 + o + 3] = val.w;
            }
        }
        __syncthreads();
        for (int j = 0; j < 64; ++j) {
            float sv = sS[r][mc * 64 + j];
            #pragma unroll
            for (int o = 0; o < 8; ++o) acc[o] += sv * bt[j][c * 8 + o];
        }
        __syncthreads();
    }

    // phase 4: depthwise conv-33 residual from v rows [r0-16, r0+48)
    {
        int row = t >> 2, col0 = (t & 3) * 16;
        int gr = r0 - 16 + row;
        bool ok = (gr >= 0) && (gr < N_SEQ);
        const float* src = v + ((size_t)bh * N_SEQ + gr) * DHEAD + col0;
        #pragma unroll
        for (int o = 0; o < 16; o += 4) {
            float4 val = ok ? *(const float4*)(src + o) : make_float4(0.f, 0.f, 0.f, 0.f);
            bt[row][col0 + o + 0] = val.x; bt[row][col0 + o + 1] = val.y;
            bt[row][col0 + o + 2] = val.z; bt[row][col0 + o + 3] = val.w;
        }
    }
    __syncthreads();
    float res[8] = {0, 0, 0, 0, 0, 0, 0, 0};
    for (int dk = 0; dk < 33; ++dk) {
        float w = wgt[dk];
        #pragma unroll
        for (int o = 0; o < 8; ++o) res[o] += w * bt[r + dk][c * 8 + o];
    }
    float inv = 1.0f / rowsum[r];
    float* dst = out + ((size_t)bh * N_SEQ + r0 + r) * DHEAD + c * 8;
    #pragma unroll
    for (int o = 0; o < 8; ++o) dst[o] = acc[o] * inv + res[o];
}

// ---------------------------------------------------------------------------
// launch
// ---------------------------------------------------------------------------
extern "C" void kernel_launch(void* const* d_in, const int* in_sizes, int n_in,
                              void* d_out, int out_size, void* d_ws, size_t ws_size,
                              hipStream_t stream)
{
    (void)in_sizes; (void)n_in; (void)out_size; (void)ws_size;
    const float* q  = (const float*)d_in[0];
    const float* k  = (const float*)d_in[1];
    const float* v  = (const float*)d_in[2];
    const float* cw = (const float*)d_in[3];
    float* out = (float*)d_out;
    float* ws  = (float*)d_ws;

    const size_t LM = (size_t)NBH * MLAND * DHEAD;   // 262144 floats
    const size_t MM = (size_t)NBH * MLAND * MLAND;   // 1048576 floats
    float* ql  = ws;
    float* kl  = ql  + LM;
    float* x   = kl  + LM;   // attn2
    float* z   = x   + MM;
    float* z2  = z   + MM;
    float* xz  = z2  + MM;
    float* t2  = xz  + MM;
    float* t3  = t2  + MM;
    float* kv  = t3  + MM;
    float* W   = kv  + LM;
    float* scl = W   + LM;   // 2 floats; total ~29.4 MB

    hipMemsetAsync(scl, 0, 2 * sizeof(float), stream);

    k_landmarks<<<dim3(NBH * MLAND, 2), 64, 0, stream>>>(q, k, ql, kl);
    k_sim2_softmax<<<NBH * MLAND, 256, 0, stream>>>(ql, kl, x);
    k_scale_reduce<<<NBH, 256, 0, stream>>>(x, scl);
    k_zinit<<<dim3(8, 8, NBH), 256, 0, stream>>>(x, z, scl);
    k_attn3_kv<<<dim3(32, NBH), 256, 0, stream>>>(ql, k, v, kv);

    // Moore-Penrose: z' = 0.25*z@(13I - xz@(15I - xz@(7I - xz))), xz = x@z
    float* zc = z;
    float* zn = z2;
    for (int it = 0; it < 6; ++it) {
        k_bmm_affine<<<dim3(4, 4, NBH), 256, 0, stream>>>(x,  zc, xz, 256, 256, 256,  0.f,  1.f, 1.f);
        k_bmm_affine<<<dim3(4, 4, NBH), 256, 0, stream>>>(xz, xz, t2, 256, 256, 256,  7.f, -1.f, 1.f);
        k_bmm_affine<<<dim3(4, 4, NBH), 256, 0, stream>>>(xz, t2, t3, 256, 256, 256, 15.f, -1.f, 1.f);
        k_bmm_affine<<<dim3(4, 4, NBH), 256, 0, stream>>>(zc, t3, zn, 256, 256, 256, 13.f, -1.f, 0.25f);
        float* tt = zc; zc = zn; zn = tt;
    }
    // W = attn2_inv @ kv   [256x256 @ 256x64]
    k_bmm_affine<<<dim3(1, 4, NBH), 256, 0, stream>>>(zc, kv, W, 256, 64, 256, 0.f, 1.f, 1.f);

    k_attn1_out<<<dim3(256, NBH), 256, 0, stream>>>(q, kl, W, v, cw, out);
}

// Round 2
// 1387.784 us; speedup vs baseline: 5.6838x; 5.6838x over previous
//
#include <hip/hip_runtime.h>

// ---------------------------------------------------------------------------
// Nystrom attention, fp32 baseline.
// b=2, h=8, n=8192, d=64, m=256 landmarks, l=32, conv kernel 33 (pad 16).
// bh = b*h = 16 flattened batch-head index throughout.
// ---------------------------------------------------------------------------

#define N_SEQ 8192
#define NBH   16
#define MLAND 256
#define DHEAD 64

// ---------------------------------------------------------------------------
// 1) landmark means: ql/kl[bh,mi,d] = mean over 32 rows of q/k
//    grid (NBH*MLAND, 2), block 64
// ---------------------------------------------------------------------------
__global__ __launch_bounds__(64) void k_landmarks(
    const float* __restrict__ q, const float* __restrict__ k,
    float* __restrict__ ql, float* __restrict__ kl)
{
    int mi = blockIdx.x & 255;
    int bh = blockIdx.x >> 8;
    const float* src = blockIdx.y ? k : q;
    float*       dst = blockIdx.y ? kl : ql;
    int t = threadIdx.x;
    const float* s = src + ((size_t)bh * N_SEQ + (size_t)mi * 32) * DHEAD;
    float acc = 0.f;
    #pragma unroll
    for (int j = 0; j < 32; ++j) acc += s[j * DHEAD + t];
    dst[((size_t)bh * MLAND + mi) * DHEAD + t] = acc * (1.f / 32.f);
}

// ---------------------------------------------------------------------------
// 2) attn2 = softmax(ql @ kl^T) rowwise. One block per (bh,row), 256 threads.
// ---------------------------------------------------------------------------
__global__ __launch_bounds__(256) void k_sim2_softmax(
    const float* __restrict__ ql, const float* __restrict__ kl,
    float* __restrict__ attn2)
{
    int bh = blockIdx.x >> 8;
    int i  = blockIdx.x & 255;
    int t  = threadIdx.x;           // landmark j
    __shared__ float qrow[DHEAD];
    __shared__ float wred[8];
    if (t < DHEAD) qrow[t] = ql[((size_t)bh * MLAND + i) * DHEAD + t];
    __syncthreads();
    const float* krow = kl + ((size_t)bh * MLAND + t) * DHEAD;
    float s = 0.f;
    #pragma unroll
    for (int kk = 0; kk < DHEAD; kk += 4) {
        float4 k4 = *(const float4*)(krow + kk);
        s += qrow[kk] * k4.x + qrow[kk + 1] * k4.y + qrow[kk + 2] * k4.z + qrow[kk + 3] * k4.w;
    }
    // block max
    float m = s;
    #pragma unroll
    for (int o = 32; o > 0; o >>= 1) m = fmaxf(m, __shfl_xor(m, o, 64));
    int wave = t >> 6, lane = t & 63;
    if (lane == 0) wred[wave] = m;
    __syncthreads();
    float bm = fmaxf(fmaxf(wred[0], wred[1]), fmaxf(wred[2], wred[3]));
    float e = __expf(s - bm);
    float sum = e;
    #pragma unroll
    for (int o = 32; o > 0; o >>= 1) sum += __shfl_xor(sum, o, 64);
    if (lane == 0) wred[4 + wave] = sum;
    __syncthreads();
    float bs = wred[4] + wred[5] + wred[6] + wred[7];
    attn2[((size_t)bh * MLAND + i) * MLAND + t] = e / bs;
}

// ---------------------------------------------------------------------------
// 3a) global max of row-sums and col-sums of attn2 (all positive).
// ---------------------------------------------------------------------------
__global__ __launch_bounds__(256) void k_scale_reduce(
    const float* __restrict__ x, float* __restrict__ scl)
{
    int bh = blockIdx.x, t = threadIdx.x;
    const float* xb = x + (size_t)bh * MLAND * MLAND;
    float colsum = 0.f, rowsum = 0.f;
    for (int i = 0; i < MLAND; ++i) colsum += xb[(size_t)i * MLAND + t];  // column t
    for (int j = 0; j < MLAND; ++j) rowsum += xb[(size_t)t * MLAND + j];  // row t
    __shared__ float red[256];
    red[t] = rowsum;
    __syncthreads();
    for (int o = 128; o > 0; o >>= 1) {
        if (t < o) red[t] = fmaxf(red[t], red[t + o]);
        __syncthreads();
    }
    if (t == 0) atomicMax((unsigned int*)&scl[0], __float_as_uint(red[0]));
    __syncthreads();
    red[t] = colsum;
    __syncthreads();
    for (int o = 128; o > 0; o >>= 1) {
        if (t < o) red[t] = fmaxf(red[t], red[t + o]);
        __syncthreads();
    }
    if (t == 0) atomicMax((unsigned int*)&scl[1], __float_as_uint(red[0]));
}

// ---------------------------------------------------------------------------
// 3b) z0 = attn2^T / (scl[0]*scl[1]). 32x32 smem transpose tiles.
// ---------------------------------------------------------------------------
__global__ __launch_bounds__(256) void k_zinit(
    const float* __restrict__ x, float* __restrict__ z,
    const float* __restrict__ scl)
{
    __shared__ float tile[32][33];
    int bh = blockIdx.z;
    int i0 = blockIdx.y * 32, j0 = blockIdx.x * 32;
    int t = threadIdx.x;
    int lx = t & 31, ly = t >> 5;  // 32 x 8, 4 passes
    const float* xb = x + (size_t)bh * MLAND * MLAND;
    float*       zb = z + (size_t)bh * MLAND * MLAND;
    #pragma unroll
    for (int p = 0; p < 4; ++p)
        tile[ly + 8 * p][lx] = xb[(size_t)(i0 + ly + 8 * p) * MLAND + j0 + lx];
    __syncthreads();
    float inv = 1.0f / (scl[0] * scl[1]);
    #pragma unroll
    for (int p = 0; p < 4; ++p)
        zb[(size_t)(j0 + ly + 8 * p) * MLAND + i0 + lx] = tile[lx][ly + 8 * p] * inv;
}

// ---------------------------------------------------------------------------
// 4) batched C = outscale * (A @ (diag*I + bscale*B)); 64x64 tiles, K-chunks 16.
// ---------------------------------------------------------------------------
__global__ __launch_bounds__(256) void k_bmm_affine(
    const float* __restrict__ A, const float* __restrict__ B, float* __restrict__ C,
    int M, int N, int K, float diag, float bscale, float outscale)
{
    __shared__ __align__(16) float As[16][68];  // [k][m]
    __shared__ __align__(16) float Bs[16][68];  // [k][n]
    int bh = blockIdx.z;
    const float* Ab = A + (size_t)bh * M * K;
    const float* Bb = B + (size_t)bh * K * N;
    float*       Cb = C + (size_t)bh * M * N;
    int m0 = blockIdx.y * 64, n0 = blockIdx.x * 64;
    int t = threadIdx.x;
    int tx = t & 15, ty = t >> 4;
    float acc[4][4] = {};
    for (int k0 = 0; k0 < K; k0 += 16) {
        {   // stage A tile (transposed into [k][m])
            int mm = t >> 2, kk0 = (t & 3) * 4;
            float4 av = *(const float4*)&Ab[(size_t)(m0 + mm) * K + k0 + kk0];
            As[kk0 + 0][mm] = av.x; As[kk0 + 1][mm] = av.y;
            As[kk0 + 2][mm] = av.z; As[kk0 + 3][mm] = av.w;
        }
        {   // stage B tile with fused affine (diag*I + bscale*B)
            int kk = t >> 4, nn0 = (t & 15) * 4;
            float4 bv = *(const float4*)&Bb[(size_t)(k0 + kk) * N + n0 + nn0];
            float rr[4] = {bv.x, bv.y, bv.z, bv.w};
            #pragma unroll
            for (int o = 0; o < 4; ++o) {
                float val = bscale * rr[o];
                if (k0 + kk == n0 + nn0 + o) val += diag;
                Bs[kk][nn0 + o] = val;
            }
        }
        __syncthreads();
        #pragma unroll
        for (int kk = 0; kk < 16; ++kk) {
            float4 a4 = *(const float4*)&As[kk][ty * 4];
            float4 b4 = *(const float4*)&Bs[kk][tx * 4];
            float a[4] = {a4.x, a4.y, a4.z, a4.w};
            float b[4] = {b4.x, b4.y, b4.z, b4.w};
            #pragma unroll
            for (int i = 0; i < 4; ++i)
                #pragma unroll
                for (int j = 0; j < 4; ++j) acc[i][j] += a[i] * b[j];
        }
        __syncthreads();
    }
    #pragma unroll
    for (int i = 0; i < 4; ++i) {
        float4 cv = make_float4(acc[i][0] * outscale, acc[i][1] * outscale,
                                acc[i][2] * outscale, acc[i][3] * outscale);
        *(float4*)&Cb[(size_t)(m0 + ty * 4 + i) * N + n0 + tx * 4] = cv;
    }
}

// ---------------------------------------------------------------------------
// 5) kv = softmax(ql @ k^T) @ v, fused online-softmax (flash) over n.
// ---------------------------------------------------------------------------
__global__ __launch_bounds__(256) void k_attn3_kv(
    const float* __restrict__ ql, const float* __restrict__ k,
    const float* __restrict__ v, float* __restrict__ kv)
{
    int bh = blockIdx.y;
    int g0 = blockIdx.x * 8;
    int t = threadIdx.x;
    __shared__ float qs[8][65];
    __shared__ float kc[64][65];
    __shared__ __align__(16) float vc[64][64];
    __shared__ float pp[8][64];
    __shared__ float Mg[8], Sg[8], nM[8], al[8];

    for (int idx = t; idx < 8 * DHEAD; idx += 256) {
        int g = idx >> 6, col = idx & 63;
        qs[g][col] = ql[((size_t)bh * MLAND + g0 + g) * DHEAD + col];
    }
    if (t < 8) { Mg[t] = -1e30f; Sg[t] = 0.f; }
    float acc1 = 0.f, acc2 = 0.f;
    int gA = t >> 6, gB = gA + 4, d = t & 63;
    const float* kb = k + (size_t)bh * N_SEQ * DHEAD;
    const float* vb = v + (size_t)bh * N_SEQ * DHEAD;
    __syncthreads();

    for (int c0 = 0; c0 < N_SEQ; c0 += 64) {
        {   // stage K/V chunk
            int row = t >> 2, col0 = (t & 3) * 16;
            const float* srck = kb + (size_t)(c0 + row) * DHEAD + col0;
            const float* srcv = vb + (size_t)(c0 + row) * DHEAD + col0;
            #pragma unroll
            for (int o = 0; o < 16; o += 4) {
                float4 val = *(const float4*)(srck + o);
                kc[row][col0 + o + 0] = val.x; kc[row][col0 + o + 1] = val.y;
                kc[row][col0 + o + 2] = val.z; kc[row][col0 + o + 3] = val.w;
            }
            #pragma unroll
            for (int o = 0; o < 16; o += 4)
                *(float4*)&vc[row][col0 + o] = *(const float4*)(srcv + o);
        }
        __syncthreads();
        #pragma unroll
        for (int half = 0; half < 2; ++half) {
            int g = (t >> 6) + half * 4;
            int j = t & 63;
            float s = 0.f;
            #pragma unroll 8
            for (int kk = 0; kk < DHEAD; ++kk) s += qs[g][kk] * kc[j][kk];
            pp[g][j] = s;
        }
        __syncthreads();
        {
            int g = t >> 5, cc = t & 31;
            float mv = fmaxf(pp[g][cc], pp[g][cc + 32]);
            #pragma unroll
            for (int o = 16; o > 0; o >>= 1) mv = fmaxf(mv, __shfl_xor(mv, o, 32));
            if (cc == 0) {
                float nm = fmaxf(Mg[g], mv);
                nM[g] = nm;
                al[g] = __expf(Mg[g] - nm);
            }
        }
        __syncthreads();
        #pragma unroll
        for (int half = 0; half < 2; ++half) {
            int g = (t >> 6) + half * 4;
            int j = t & 63;
            pp[g][j] = __expf(pp[g][j] - nM[g]);
        }
        acc1 *= al[gA]; acc2 *= al[gB];
        __syncthreads();
        {
            int g = t >> 5, cc = t & 31;
            float sv = pp[g][cc] + pp[g][cc + 32];
            #pragma unroll
            for (int o = 16; o > 0; o >>= 1) sv += __shfl_xor(sv, o, 32);
            if (cc == 0) { Sg[g] = Sg[g] * al[g] + sv; Mg[g] = nM[g]; }
        }
        #pragma unroll 8
        for (int j = 0; j < 64; ++j) {
            float vv = vc[j][d];
            acc1 += pp[gA][j] * vv;
            acc2 += pp[gB][j] * vv;
        }
        __syncthreads();
    }
    kv[((size_t)bh * MLAND + g0 + gA) * DHEAD + d] = acc1 / Sg[gA];
    kv[((size_t)bh * MLAND + g0 + gB) * DHEAD + d] = acc2 / Sg[gB];
}

// ---------------------------------------------------------------------------
// 6) out = softmax(q @ kl^T) @ W + depthwise-conv33(v).  REWRITTEN.
//    32 q-rows per block, 256 threads (ty=t>>4 in 0..15 -> rows {ty,ty+16};
//    tx=t&15 -> cols tx*4). Register micro-tile 2x4 (8 accs) - no spills.
//    __launch_bounds__(256,4) caps VGPR at 128. LDS ~60.7 KB -> 2 blocks/CU.
// ---------------------------------------------------------------------------
__global__ __launch_bounds__(256, 4) void k_attn1_out(
    const float* __restrict__ q, const float* __restrict__ kl,
    const float* __restrict__ W, const float* __restrict__ v,
    const float* __restrict__ cw, float* __restrict__ out)
{
    int bh = blockIdx.y;
    int r0 = blockIdx.x * 32;
    int h  = bh & 7;
    int t  = threadIdx.x;
    int ty = t >> 4, tx = t & 15;

    __shared__ float qs[64][36];                  // q tile transposed [k][m]
    __shared__ __align__(16) float bs[64][68];    // kl^T chunk / W chunk / v rows
    __shared__ __align__(16) float sS[32][264];   // scores -> exp(scores)
    __shared__ float rowsum[32];
    __shared__ float wgt[33];

    if (t < 33) wgt[t] = cw[h * 33 + t];
    {   // stage q tile transposed: thread loads 8 k-values of one row
        int m = t & 31, k0 = (t >> 5) * 8;
        const float* src = q + ((size_t)bh * N_SEQ + r0 + m) * DHEAD + k0;
        float4 a = *(const float4*)src;
        float4 b = *(const float4*)(src + 4);
        qs[k0 + 0][m] = a.x; qs[k0 + 1][m] = a.y; qs[k0 + 2][m] = a.z; qs[k0 + 3][m] = a.w;
        qs[k0 + 4][m] = b.x; qs[k0 + 5][m] = b.y; qs[k0 + 6][m] = b.z; qs[k0 + 7][m] = b.w;
    }

    // phase 1: S = q_tile @ kl^T, 4 chunks of 64 landmarks
    for (int mc = 0; mc < 4; ++mc) {
        __syncthreads();
        {   // stage kl^T chunk into bs[k][n]
            int n = t & 63, k0 = (t >> 6) * 16;
            const float* src = kl + ((size_t)bh * MLAND + mc * 64 + n) * DHEAD + k0;
            #pragma unroll
            for (int o = 0; o < 16; o += 4) {
                float4 val = *(const float4*)(src + o);
                bs[k0 + o + 0][n] = val.x; bs[k0 + o + 1][n] = val.y;
                bs[k0 + o + 2][n] = val.z; bs[k0 + o + 3][n] = val.w;
            }
        }
        __syncthreads();
        float a00 = 0.f, a01 = 0.f, a02 = 0.f, a03 = 0.f;
        float a10 = 0.f, a11 = 0.f, a12 = 0.f, a13 = 0.f;
        #pragma unroll 4
        for (int kk = 0; kk < DHEAD; ++kk) {
            float q0 = qs[kk][ty];
            float q1 = qs[kk][ty + 16];
            float4 b4 = *(const float4*)&bs[kk][tx * 4];
            a00 += q0 * b4.x; a01 += q0 * b4.y; a02 += q0 * b4.z; a03 += q0 * b4.w;
            a10 += q1 * b4.x; a11 += q1 * b4.y; a12 += q1 * b4.z; a13 += q1 * b4.w;
        }
        *(float4*)&sS[ty][mc * 64 + tx * 4]      = make_float4(a00, a01, a02, a03);
        *(float4*)&sS[ty + 16][mc * 64 + tx * 4] = make_float4(a10, a11, a12, a13);
    }
    __syncthreads();

    // phase 2: rowwise softmax (8 lanes per row), keep unnormalized exp
    {
        int r = t >> 3, c = t & 7;
        float mv = -1e30f;
        for (int j = c; j < MLAND; j += 8) mv = fmaxf(mv, sS[r][j]);
        #pragma unroll
        for (int o = 4; o > 0; o >>= 1) mv = fmaxf(mv, __shfl_xor(mv, o, 8));
        float sum = 0.f;
        for (int j = c; j < MLAND; j += 8) {
            float e = __expf(sS[r][j] - mv);
            sS[r][j] = e;
            sum += e;
        }
        #pragma unroll
        for (int o = 4; o > 0; o >>= 1) sum += __shfl_xor(sum, o, 8);
        if (c == 0) rowsum[r] = sum;
    }

    // phase 3: out_tile = P @ W, 4 chunks of 64 W-rows (natural layout)
    float o00 = 0.f, o01 = 0.f, o02 = 0.f, o03 = 0.f;
    float o10 = 0.f, o11 = 0.f, o12 = 0.f, o13 = 0.f;
    for (int mc = 0; mc < 4; ++mc) {
        __syncthreads();
        {   // stage W chunk rows into bs[j][d]
            int row = t >> 2, col0 = (t & 3) * 16;
            const float* src = W + ((size_t)bh * MLAND + mc * 64 + row) * DHEAD + col0;
            #pragma unroll
            for (int o = 0; o < 16; o += 4)
                *(float4*)&bs[row][col0 + o] = *(const float4*)(src + o);
        }
        __syncthreads();
        #pragma unroll 4
        for (int j = 0; j < 64; ++j) {
            float p0 = sS[ty][mc * 64 + j];
            float p1 = sS[ty + 16][mc * 64 + j];
            float4 w4 = *(const float4*)&bs[j][tx * 4];
            o00 += p0 * w4.x; o01 += p0 * w4.y; o02 += p0 * w4.z; o03 += p0 * w4.w;
            o10 += p1 * w4.x; o11 += p1 * w4.y; o12 += p1 * w4.z; o13 += p1 * w4.w;
        }
    }
    __syncthreads();

    // phase 4: depthwise conv-33 residual from v rows [r0-16, r0+48)
    {
        int row = t >> 2, col0 = (t & 3) * 16;
        int gr = r0 - 16 + row;
        bool ok = (gr >= 0) && (gr < N_SEQ);
        const float* src = v + ((size_t)bh * N_SEQ + gr) * DHEAD + col0;
        #pragma unroll
        for (int o = 0; o < 16; o += 4) {
            float4 val = ok ? *(const float4*)(src + o) : make_float4(0.f, 0.f, 0.f, 0.f);
            *(float4*)&bs[row][col0 + o] = val;
        }
    }
    __syncthreads();
    float r00 = 0.f, r01 = 0.f, r02 = 0.f, r03 = 0.f;
    float r10 = 0.f, r11 = 0.f, r12 = 0.f, r13 = 0.f;
    for (int dk = 0; dk < 33; ++dk) {
        float w = wgt[dk];
        float4 v0 = *(const float4*)&bs[ty + dk][tx * 4];
        float4 v1 = *(const float4*)&bs[ty + 16 + dk][tx * 4];
        r00 += w * v0.x; r01 += w * v0.y; r02 += w * v0.z; r03 += w * v0.w;
        r10 += w * v1.x; r11 += w * v1.y; r12 += w * v1.z; r13 += w * v1.w;
    }

    float inv0 = 1.0f / rowsum[ty];
    float inv1 = 1.0f / rowsum[ty + 16];
    float* dst0 = out + ((size_t)bh * N_SEQ + r0 + ty) * DHEAD + tx * 4;
    float* dst1 = out + ((size_t)bh * N_SEQ + r0 + ty + 16) * DHEAD + tx * 4;
    *(float4*)dst0 = make_float4(o00 * inv0 + r00, o01 * inv0 + r01,
                                 o02 * inv0 + r02, o03 * inv0 + r03);
    *(float4*)dst1 = make_float4(o10 * inv1 + r10, o11 * inv1 + r11,
                                 o12 * inv1 + r12, o13 * inv1 + r13);
}

// ---------------------------------------------------------------------------
// launch
// ---------------------------------------------------------------------------
extern "C" void kernel_launch(void* const* d_in, const int* in_sizes, int n_in,
                              void* d_out, int out_size, void* d_ws, size_t ws_size,
                              hipStream_t stream)
{
    (void)in_sizes; (void)n_in; (void)out_size; (void)ws_size;
    const float* q  = (const float*)d_in[0];
    const float* k  = (const float*)d_in[1];
    const float* v  = (const float*)d_in[2];
    const float* cw = (const float*)d_in[3];
    float* out = (float*)d_out;
    float* ws  = (float*)d_ws;

    const size_t LM = (size_t)NBH * MLAND * DHEAD;   // 262144 floats
    const size_t MM = (size_t)NBH * MLAND * MLAND;   // 1048576 floats
    float* ql  = ws;
    float* kl  = ql  + LM;
    float* x   = kl  + LM;   // attn2
    float* z   = x   + MM;
    float* z2  = z   + MM;
    float* xz  = z2  + MM;
    float* t2  = xz  + MM;
    float* t3  = t2  + MM;
    float* kv  = t3  + MM;
    float* W   = kv  + LM;
    float* scl = W   + LM;   // 2 floats

    hipMemsetAsync(scl, 0, 2 * sizeof(float), stream);

    k_landmarks<<<dim3(NBH * MLAND, 2), 64, 0, stream>>>(q, k, ql, kl);
    k_sim2_softmax<<<NBH * MLAND, 256, 0, stream>>>(ql, kl, x);
    k_scale_reduce<<<NBH, 256, 0, stream>>>(x, scl);
    k_zinit<<<dim3(8, 8, NBH), 256, 0, stream>>>(x, z, scl);
    k_attn3_kv<<<dim3(32, NBH), 256, 0, stream>>>(ql, k, v, kv);

    // Moore-Penrose: z' = 0.25*z@(13I - xz@(15I - xz@(7I - xz))), xz = x@z
    float* zc = z;
    float* zn = z2;
    for (int it = 0; it < 6; ++it) {
        k_bmm_affine<<<dim3(4, 4, NBH), 256, 0, stream>>>(x,  zc, xz, 256, 256, 256,  0.f,  1.f, 1.f);
        k_bmm_affine<<<dim3(4, 4, NBH), 256, 0, stream>>>(xz, xz, t2, 256, 256, 256,  7.f, -1.f, 1.f);
        k_bmm_affine<<<dim3(4, 4, NBH), 256, 0, stream>>>(xz, t2, t3, 256, 256, 256, 15.f, -1.f, 1.f);
        k_bmm_affine<<<dim3(4, 4, NBH), 256, 0, stream>>>(zc, t3, zn, 256, 256, 256, 13.f, -1.f, 0.25f);
        float* tt = zc; zc = zn; zn = tt;
    }
    // W = attn2_inv @ kv   [256x256 @ 256x64]
    k_bmm_affine<<<dim3(1, 4, NBH), 256, 0, stream>>>(zc, kv, W, 256, 64, 256, 0.f, 1.f, 1.f);

    k_attn1_out<<<dim3(256, NBH), 256, 0, stream>>>(q, kl, W, v, cw, out);
}

// Round 3
// 948.069 us; speedup vs baseline: 8.3199x; 1.4638x over previous
//
#include <hip/hip_runtime.h>

// ---------------------------------------------------------------------------
// Nystrom attention, fp32.
// b=2, h=8, n=8192, d=64, m=256 landmarks, l=32, conv kernel 33 (pad 16).
// ---------------------------------------------------------------------------

#define N_SEQ 8192
#define NBH   16
#define MLAND 256
#define DHEAD 64

// ---------------------------------------------------------------------------
// 1) landmark means
// ---------------------------------------------------------------------------
__global__ __launch_bounds__(64) void k_landmarks(
    const float* __restrict__ q, const float* __restrict__ k,
    float* __restrict__ ql, float* __restrict__ kl)
{
    int mi = blockIdx.x & 255;
    int bh = blockIdx.x >> 8;
    const float* src = blockIdx.y ? k : q;
    float*       dst = blockIdx.y ? kl : ql;
    int t = threadIdx.x;
    const float* s = src + ((size_t)bh * N_SEQ + (size_t)mi * 32) * DHEAD;
    float acc = 0.f;
    #pragma unroll
    for (int j = 0; j < 32; ++j) acc += s[j * DHEAD + t];
    dst[((size_t)bh * MLAND + mi) * DHEAD + t] = acc * (1.f / 32.f);
}

// ---------------------------------------------------------------------------
// 2) attn2 = softmax(ql @ kl^T) rowwise
// ---------------------------------------------------------------------------
__global__ __launch_bounds__(256) void k_sim2_softmax(
    const float* __restrict__ ql, const float* __restrict__ kl,
    float* __restrict__ attn2)
{
    int bh = blockIdx.x >> 8;
    int i  = blockIdx.x & 255;
    int t  = threadIdx.x;
    __shared__ float qrow[DHEAD];
    __shared__ float wred[8];
    if (t < DHEAD) qrow[t] = ql[((size_t)bh * MLAND + i) * DHEAD + t];
    __syncthreads();
    const float* krow = kl + ((size_t)bh * MLAND + t) * DHEAD;
    float s = 0.f;
    #pragma unroll
    for (int kk = 0; kk < DHEAD; kk += 4) {
        float4 k4 = *(const float4*)(krow + kk);
        s += qrow[kk] * k4.x + qrow[kk + 1] * k4.y + qrow[kk + 2] * k4.z + qrow[kk + 3] * k4.w;
    }
    float m = s;
    #pragma unroll
    for (int o = 32; o > 0; o >>= 1) m = fmaxf(m, __shfl_xor(m, o, 64));
    int wave = t >> 6, lane = t & 63;
    if (lane == 0) wred[wave] = m;
    __syncthreads();
    float bm = fmaxf(fmaxf(wred[0], wred[1]), fmaxf(wred[2], wred[3]));
    float e = __expf(s - bm);
    float sum = e;
    #pragma unroll
    for (int o = 32; o > 0; o >>= 1) sum += __shfl_xor(sum, o, 64);
    if (lane == 0) wred[4 + wave] = sum;
    __syncthreads();
    float bs = wred[4] + wred[5] + wred[6] + wred[7];
    attn2[((size_t)bh * MLAND + i) * MLAND + t] = e / bs;
}

// ---------------------------------------------------------------------------
// 3a) global max of row-sums and col-sums of attn2
// ---------------------------------------------------------------------------
__global__ __launch_bounds__(256) void k_scale_reduce(
    const float* __restrict__ x, float* __restrict__ scl)
{
    int bh = blockIdx.x, t = threadIdx.x;
    const float* xb = x + (size_t)bh * MLAND * MLAND;
    float colsum = 0.f, rowsum = 0.f;
    for (int i = 0; i < MLAND; ++i) colsum += xb[(size_t)i * MLAND + t];
    for (int j = 0; j < MLAND; ++j) rowsum += xb[(size_t)t * MLAND + j];
    __shared__ float red[256];
    red[t] = rowsum;
    __syncthreads();
    for (int o = 128; o > 0; o >>= 1) {
        if (t < o) red[t] = fmaxf(red[t], red[t + o]);
        __syncthreads();
    }
    if (t == 0) atomicMax((unsigned int*)&scl[0], __float_as_uint(red[0]));
    __syncthreads();
    red[t] = colsum;
    __syncthreads();
    for (int o = 128; o > 0; o >>= 1) {
        if (t < o) red[t] = fmaxf(red[t], red[t + o]);
        __syncthreads();
    }
    if (t == 0) atomicMax((unsigned int*)&scl[1], __float_as_uint(red[0]));
}

// ---------------------------------------------------------------------------
// 3b) z0 = attn2^T / (scl[0]*scl[1])
// ---------------------------------------------------------------------------
__global__ __launch_bounds__(256) void k_zinit(
    const float* __restrict__ x, float* __restrict__ z,
    const float* __restrict__ scl)
{
    __shared__ float tile[32][33];
    int bh = blockIdx.z;
    int i0 = blockIdx.y * 32, j0 = blockIdx.x * 32;
    int t = threadIdx.x;
    int lx = t & 31, ly = t >> 5;
    const float* xb = x + (size_t)bh * MLAND * MLAND;
    float*       zb = z + (size_t)bh * MLAND * MLAND;
    #pragma unroll
    for (int p = 0; p < 4; ++p)
        tile[ly + 8 * p][lx] = xb[(size_t)(i0 + ly + 8 * p) * MLAND + j0 + lx];
    __syncthreads();
    float inv = 1.0f / (scl[0] * scl[1]);
    #pragma unroll
    for (int p = 0; p < 4; ++p)
        zb[(size_t)(j0 + ly + 8 * p) * MLAND + i0 + lx] = tile[lx][ly + 8 * p] * inv;
}

// ---------------------------------------------------------------------------
// 4) batched C = outscale * (A @ (diag*I + bscale*B)); 64x64 tiles
// ---------------------------------------------------------------------------
__global__ __launch_bounds__(256) void k_bmm_affine(
    const float* __restrict__ A, const float* __restrict__ B, float* __restrict__ C,
    int M, int N, int K, float diag, float bscale, float outscale)
{
    __shared__ __align__(16) float As[16][68];
    __shared__ __align__(16) float Bs[16][68];
    int bh = blockIdx.z;
    const float* Ab = A + (size_t)bh * M * K;
    const float* Bb = B + (size_t)bh * K * N;
    float*       Cb = C + (size_t)bh * M * N;
    int m0 = blockIdx.y * 64, n0 = blockIdx.x * 64;
    int t = threadIdx.x;
    int tx = t & 15, ty = t >> 4;
    float acc[4][4] = {};
    for (int k0 = 0; k0 < K; k0 += 16) {
        {
            int mm = t >> 2, kk0 = (t & 3) * 4;
            float4 av = *(const float4*)&Ab[(size_t)(m0 + mm) * K + k0 + kk0];
            As[kk0 + 0][mm] = av.x; As[kk0 + 1][mm] = av.y;
            As[kk0 + 2][mm] = av.z; As[kk0 + 3][mm] = av.w;
        }
        {
            int kk = t >> 4, nn0 = (t & 15) * 4;
            float4 bv = *(const float4*)&Bb[(size_t)(k0 + kk) * N + n0 + nn0];
            float rr[4] = {bv.x, bv.y, bv.z, bv.w};
            #pragma unroll
            for (int o = 0; o < 4; ++o) {
                float val = bscale * rr[o];
                if (k0 + kk == n0 + nn0 + o) val += diag;
                Bs[kk][nn0 + o] = val;
            }
        }
        __syncthreads();
        #pragma unroll
        for (int kk = 0; kk < 16; ++kk) {
            float4 a4 = *(const float4*)&As[kk][ty * 4];
            float4 b4 = *(const float4*)&Bs[kk][tx * 4];
            float a[4] = {a4.x, a4.y, a4.z, a4.w};
            float b[4] = {b4.x, b4.y, b4.z, b4.w};
            #pragma unroll
            for (int i = 0; i < 4; ++i)
                #pragma unroll
                for (int j = 0; j < 4; ++j) acc[i][j] += a[i] * b[j];
        }
        __syncthreads();
    }
    #pragma unroll
    for (int i = 0; i < 4; ++i) {
        float4 cv = make_float4(acc[i][0] * outscale, acc[i][1] * outscale,
                                acc[i][2] * outscale, acc[i][3] * outscale);
        *(float4*)&Cb[(size_t)(m0 + ty * 4 + i) * N + n0 + tx * 4] = cv;
    }
}

// ---------------------------------------------------------------------------
// 5a) attn3 flash partial: per (m-tile 64, n-split 1024, bh) compute
//     running-max softmax partials: pm (max), pl (sum), pO (unnormalized O).
//     grid (4, 8, NBH), block 256 = (ty 0..15, tx 0..15), 4x4 micro-tile.
// ---------------------------------------------------------------------------
__global__ __launch_bounds__(256, 4) void k_attn3_partial(
    const float* __restrict__ ql, const float* __restrict__ k,
    const float* __restrict__ v, float* __restrict__ pO,
    float* __restrict__ pm, float* __restrict__ pl)
{
    int mt = blockIdx.x;
    int sp = blockIdx.y;
    int bh = blockIdx.z;
    int m0 = mt * 64;
    int n0 = sp * 1024;
    int t = threadIdx.x;
    int ty = t >> 4, tx = t & 15;

    __shared__ __align__(16) float qs[64][68];   // Q natural [m][kk]
    __shared__ __align__(16) float kp[64][68];   // K^T [kk][j]; reused as P [r][j]
    __shared__ __align__(16) float vc[64][68];   // V natural [j][d]

    {   // stage Q tile (once)
        int m = t & 63, k0 = (t >> 6) * 16;
        const float* src = ql + ((size_t)bh * MLAND + m0 + m) * DHEAD + k0;
        #pragma unroll
        for (int o = 0; o < 16; o += 4)
            *(float4*)&qs[m][k0 + o] = *(const float4*)(src + o);
    }

    float S[4][4];
    float O[4][4] = {};
    float M[4], L[4];
    #pragma unroll
    for (int i = 0; i < 4; ++i) { M[i] = -1e30f; L[i] = 0.f; }

    const float* kb = k + (size_t)bh * N_SEQ * DHEAD;
    const float* vb = v + (size_t)bh * N_SEQ * DHEAD;

    for (int c0 = n0; c0 < n0 + 1024; c0 += 64) {
        __syncthreads();   // prior PV reads done (and Q staging on first iter)
        {   // stage K^T and V chunk
            int row = t & 63, k0 = (t >> 6) * 16;
            const float* srck = kb + (size_t)(c0 + row) * DHEAD + k0;
            const float* srcv = vb + (size_t)(c0 + row) * DHEAD + k0;
            #pragma unroll
            for (int o = 0; o < 16; o += 4) {
                float4 val = *(const float4*)(srck + o);
                kp[k0 + o + 0][row] = val.x; kp[k0 + o + 1][row] = val.y;
                kp[k0 + o + 2][row] = val.z; kp[k0 + o + 3][row] = val.w;
            }
            #pragma unroll
            for (int o = 0; o < 16; o += 4)
                *(float4*)&vc[row][k0 + o] = *(const float4*)(srcv + o);
        }
        __syncthreads();

        // S = Q @ K^T  (rows broadcast, cols float4)
        #pragma unroll
        for (int i = 0; i < 4; ++i)
            #pragma unroll
            for (int j = 0; j < 4; ++j) S[i][j] = 0.f;
        #pragma unroll 2
        for (int kkb = 0; kkb < 16; ++kkb) {
            float4 q4[4];
            q4[0] = *(const float4*)&qs[ty     ][kkb * 4];
            q4[1] = *(const float4*)&qs[ty + 16][kkb * 4];
            q4[2] = *(const float4*)&qs[ty + 32][kkb * 4];
            q4[3] = *(const float4*)&qs[ty + 48][kkb * 4];
            #pragma unroll
            for (int ko = 0; ko < 4; ++ko) {
                float4 k4 = *(const float4*)&kp[kkb * 4 + ko][tx * 4];
                #pragma unroll
                for (int i = 0; i < 4; ++i) {
                    float qv = (&q4[i].x)[ko];
                    S[i][0] += qv * k4.x; S[i][1] += qv * k4.y;
                    S[i][2] += qv * k4.z; S[i][3] += qv * k4.w;
                }
            }
        }

        // online softmax update (per row-group i; 16 tx lanes share a row)
        #pragma unroll
        for (int i = 0; i < 4; ++i) {
            float mv = fmaxf(fmaxf(S[i][0], S[i][1]), fmaxf(S[i][2], S[i][3]));
            #pragma unroll
            for (int o = 8; o > 0; o >>= 1) mv = fmaxf(mv, __shfl_xor(mv, o, 16));
            float nM = fmaxf(M[i], mv);
            float alpha = __expf(M[i] - nM);
            M[i] = nM;
            L[i] *= alpha;
            #pragma unroll
            for (int j = 0; j < 4; ++j) {
                O[i][j] *= alpha;
                S[i][j] = __expf(S[i][j] - nM);
            }
            float rs = S[i][0] + S[i][1] + S[i][2] + S[i][3];
            #pragma unroll
            for (int o = 8; o > 0; o >>= 1) rs += __shfl_xor(rs, o, 16);
            L[i] += rs;
        }

        __syncthreads();   // all QK reads of kp done before overwrite with P
        #pragma unroll
        for (int i = 0; i < 4; ++i)
            *(float4*)&kp[ty + 16 * i][tx * 4] =
                make_float4(S[i][0], S[i][1], S[i][2], S[i][3]);
        __syncthreads();

        // O += P @ V  (P rows broadcast, V cols float4)
        #pragma unroll 2
        for (int jjb = 0; jjb < 16; ++jjb) {
            float4 p4[4];
            p4[0] = *(const float4*)&kp[ty     ][jjb * 4];
            p4[1] = *(const float4*)&kp[ty + 16][jjb * 4];
            p4[2] = *(const float4*)&kp[ty + 32][jjb * 4];
            p4[3] = *(const float4*)&kp[ty + 48][jjb * 4];
            #pragma unroll
            for (int jo = 0; jo < 4; ++jo) {
                float4 v4 = *(const float4*)&vc[jjb * 4 + jo][tx * 4];
                #pragma unroll
                for (int i = 0; i < 4; ++i) {
                    float pv = (&p4[i].x)[jo];
                    O[i][0] += pv * v4.x; O[i][1] += pv * v4.y;
                    O[i][2] += pv * v4.z; O[i][3] += pv * v4.w;
                }
            }
        }
    }

    int base = (bh * 8 + sp) * MLAND + m0;
    #pragma unroll
    for (int i = 0; i < 4; ++i) {
        int r = ty + 16 * i;
        if (tx == 0) { pm[base + r] = M[i]; pl[base + r] = L[i]; }
        *(float4*)&pO[(size_t)(base + r) * DHEAD + tx * 4] =
            make_float4(O[i][0], O[i][1], O[i][2], O[i][3]);
    }
}

// ---------------------------------------------------------------------------
// 5b) combine 8 splits -> kv. grid (NBH*MLAND), block 64 (d = lane).
// ---------------------------------------------------------------------------
__global__ __launch_bounds__(64) void k_attn3_combine(
    const float* __restrict__ pO, const float* __restrict__ pm,
    const float* __restrict__ pl, float* __restrict__ kv)
{
    int bh = blockIdx.x >> 8;
    int m  = blockIdx.x & 255;
    int d  = threadIdx.x;
    float M = -1e30f;
    #pragma unroll
    for (int s = 0; s < 8; ++s) M = fmaxf(M, pm[(bh * 8 + s) * MLAND + m]);
    float L = 0.f, O = 0.f;
    #pragma unroll
    for (int s = 0; s < 8; ++s) {
        int base = (bh * 8 + s) * MLAND + m;
        float w = __expf(pm[base] - M);
        L += pl[base] * w;
        O += w * pO[(size_t)base * DHEAD + d];
    }
    kv[((size_t)bh * MLAND + m) * DHEAD + d] = O / L;
}

// ---------------------------------------------------------------------------
// 6) out = softmax(q @ kl^T) @ W + depthwise-conv33(v)
// ---------------------------------------------------------------------------
__global__ __launch_bounds__(256, 4) void k_attn1_out(
    const float* __restrict__ q, const float* __restrict__ kl,
    const float* __restrict__ W, const float* __restrict__ v,
    const float* __restrict__ cw, float* __restrict__ out)
{
    int bh = blockIdx.y;
    int r0 = blockIdx.x * 32;
    int h  = bh & 7;
    int t  = threadIdx.x;
    int ty = t >> 4, tx = t & 15;

    __shared__ float qs[64][36];
    __shared__ __align__(16) float bs[64][68];
    __shared__ __align__(16) float sS[32][264];
    __shared__ float rowsum[32];
    __shared__ float wgt[33];

    if (t < 33) wgt[t] = cw[h * 33 + t];
    {
        int m = t & 31, k0 = (t >> 5) * 8;
        const float* src = q + ((size_t)bh * N_SEQ + r0 + m) * DHEAD + k0;
        float4 a = *(const float4*)src;
        float4 b = *(const float4*)(src + 4);
        qs[k0 + 0][m] = a.x; qs[k0 + 1][m] = a.y; qs[k0 + 2][m] = a.z; qs[k0 + 3][m] = a.w;
        qs[k0 + 4][m] = b.x; qs[k0 + 5][m] = b.y; qs[k0 + 6][m] = b.z; qs[k0 + 7][m] = b.w;
    }

    for (int mc = 0; mc < 4; ++mc) {
        __syncthreads();
        {
            int n = t & 63, k0 = (t >> 6) * 16;
            const float* src = kl + ((size_t)bh * MLAND + mc * 64 + n) * DHEAD + k0;
            #pragma unroll
            for (int o = 0; o < 16; o += 4) {
                float4 val = *(const float4*)(src + o);
                bs[k0 + o + 0][n] = val.x; bs[k0 + o + 1][n] = val.y;
                bs[k0 + o + 2][n] = val.z; bs[k0 + o + 3][n] = val.w;
            }
        }
        __syncthreads();
        float a00 = 0.f, a01 = 0.f, a02 = 0.f, a03 = 0.f;
        float a10 = 0.f, a11 = 0.f, a12 = 0.f, a13 = 0.f;
        #pragma unroll 4
        for (int kk = 0; kk < DHEAD; ++kk) {
            float q0 = qs[kk][ty];
            float q1 = qs[kk][ty + 16];
            float4 b4 = *(const float4*)&bs[kk][tx * 4];
            a00 += q0 * b4.x; a01 += q0 * b4.y; a02 += q0 * b4.z; a03 += q0 * b4.w;
            a10 += q1 * b4.x; a11 += q1 * b4.y; a12 += q1 * b4.z; a13 += q1 * b4.w;
        }
        *(float4*)&sS[ty][mc * 64 + tx * 4]      = make_float4(a00, a01, a02, a03);
        *(float4*)&sS[ty + 16][mc * 64 + tx * 4] = make_float4(a10, a11, a12, a13);
    }
    __syncthreads();

    {
        int r = t >> 3, c = t & 7;
        float mv = -1e30f;
        for (int j = c; j < MLAND; j += 8) mv = fmaxf(mv, sS[r][j]);
        #pragma unroll
        for (int o = 4; o > 0; o >>= 1) mv = fmaxf(mv, __shfl_xor(mv, o, 8));
        float sum = 0.f;
        for (int j = c; j < MLAND; j += 8) {
            float e = __expf(sS[r][j] - mv);
            sS[r][j] = e;
            sum += e;
        }
        #pragma unroll
        for (int o = 4; o > 0; o >>= 1) sum += __shfl_xor(sum, o, 8);
        if (c == 0) rowsum[r] = sum;
    }

    float o00 = 0.f, o01 = 0.f, o02 = 0.f, o03 = 0.f;
    float o10 = 0.f, o11 = 0.f, o12 = 0.f, o13 = 0.f;
    for (int mc = 0; mc < 4; ++mc) {
        __syncthreads();
        {
            int row = t >> 2, col0 = (t & 3) * 16;
            const float* src = W + ((size_t)bh * MLAND + mc * 64 + row) * DHEAD + col0;
            #pragma unroll
            for (int o = 0; o < 16; o += 4)
                *(float4*)&bs[row][col0 + o] = *(const float4*)(src + o);
        }
        __syncthreads();
        #pragma unroll 4
        for (int j = 0; j < 64; ++j) {
            float p0 = sS[ty][mc * 64 + j];
            float p1 = sS[ty + 16][mc * 64 + j];
            float4 w4 = *(const float4*)&bs[j][tx * 4];
            o00 += p0 * w4.x; o01 += p0 * w4.y; o02 += p0 * w4.z; o03 += p0 * w4.w;
            o10 += p1 * w4.x; o11 += p1 * w4.y; o12 += p1 * w4.z; o13 += p1 * w4.w;
        }
    }
    __syncthreads();

    {
        int row = t >> 2, col0 = (t & 3) * 16;
        int gr = r0 - 16 + row;
        bool ok = (gr >= 0) && (gr < N_SEQ);
        const float* src = v + ((size_t)bh * N_SEQ + gr) * DHEAD + col0;
        #pragma unroll
        for (int o = 0; o < 16; o += 4) {
            float4 val = ok ? *(const float4*)(src + o) : make_float4(0.f, 0.f, 0.f, 0.f);
            *(float4*)&bs[row][col0 + o] = val;
        }
    }
    __syncthreads();
    float r00 = 0.f, r01 = 0.f, r02 = 0.f, r03 = 0.f;
    float r10 = 0.f, r11 = 0.f, r12 = 0.f, r13 = 0.f;
    for (int dk = 0; dk < 33; ++dk) {
        float w = wgt[dk];
        float4 v0 = *(const float4*)&bs[ty + dk][tx * 4];
        float4 v1 = *(const float4*)&bs[ty + 16 + dk][tx * 4];
        r00 += w * v0.x; r01 += w * v0.y; r02 += w * v0.z; r03 += w * v0.w;
        r10 += w * v1.x; r11 += w * v1.y; r12 += w * v1.z; r13 += w * v1.w;
    }

    float inv0 = 1.0f / rowsum[ty];
    float inv1 = 1.0f / rowsum[ty + 16];
    float* dst0 = out + ((size_t)bh * N_SEQ + r0 + ty) * DHEAD + tx * 4;
    float* dst1 = out + ((size_t)bh * N_SEQ + r0 + ty + 16) * DHEAD + tx * 4;
    *(float4*)dst0 = make_float4(o00 * inv0 + r00, o01 * inv0 + r01,
                                 o02 * inv0 + r02, o03 * inv0 + r03);
    *(float4*)dst1 = make_float4(o10 * inv1 + r10, o11 * inv1 + r11,
                                 o12 * inv1 + r12, o13 * inv1 + r13);
}

// ---------------------------------------------------------------------------
// launch
// ---------------------------------------------------------------------------
extern "C" void kernel_launch(void* const* d_in, const int* in_sizes, int n_in,
                              void* d_out, int out_size, void* d_ws, size_t ws_size,
                              hipStream_t stream)
{
    (void)in_sizes; (void)n_in; (void)out_size; (void)ws_size;
    const float* q  = (const float*)d_in[0];
    const float* k  = (const float*)d_in[1];
    const float* v  = (const float*)d_in[2];
    const float* cw = (const float*)d_in[3];
    float* out = (float*)d_out;
    float* ws  = (float*)d_ws;

    const size_t LM = (size_t)NBH * MLAND * DHEAD;   // 262144 floats
    const size_t MM = (size_t)NBH * MLAND * MLAND;   // 1048576 floats
    float* ql  = ws;
    float* kl  = ql  + LM;
    float* x   = kl  + LM;   // attn2
    float* z   = x   + MM;
    float* z2  = z   + MM;
    float* xz  = z2  + MM;
    float* t2  = xz  + MM;
    float* t3  = t2  + MM;
    float* kv  = t3  + MM;
    float* W   = kv  + LM;
    float* scl = W   + LM;   // 2 floats

    // attn3 partials alias pinv scratch (first written AFTER the combine):
    // pO spans z2+xz (exactly 2*MM floats); pm/pl live at the head of t2.
    float* pO = z2;
    float* pm = t2;
    float* pl = t2 + (size_t)NBH * 8 * MLAND;

    hipMemsetAsync(scl, 0, 2 * sizeof(float), stream);

    k_landmarks<<<dim3(NBH * MLAND, 2), 64, 0, stream>>>(q, k, ql, kl);
    k_sim2_softmax<<<NBH * MLAND, 256, 0, stream>>>(ql, kl, x);
    k_scale_reduce<<<NBH, 256, 0, stream>>>(x, scl);
    k_zinit<<<dim3(8, 8, NBH), 256, 0, stream>>>(x, z, scl);

    k_attn3_partial<<<dim3(4, 8, NBH), 256, 0, stream>>>(ql, k, v, pO, pm, pl);
    k_attn3_combine<<<NBH * MLAND, 64, 0, stream>>>(pO, pm, pl, kv);

    // Moore-Penrose: z' = 0.25*z@(13I - xz@(15I - xz@(7I - xz))), xz = x@z
    float* zc = z;
    float* zn = z2;
    for (int it = 0; it < 6; ++it) {
        k_bmm_affine<<<dim3(4, 4, NBH), 256, 0, stream>>>(x,  zc, xz, 256, 256, 256,  0.f,  1.f, 1.f);
        k_bmm_affine<<<dim3(4, 4, NBH), 256, 0, stream>>>(xz, xz, t2, 256, 256, 256,  7.f, -1.f, 1.f);
        k_bmm_affine<<<dim3(4, 4, NBH), 256, 0, stream>>>(xz, t2, t3, 256, 256, 256, 15.f, -1.f, 1.f);
        k_bmm_affine<<<dim3(4, 4, NBH), 256, 0, stream>>>(zc, t3, zn, 256, 256, 256, 13.f, -1.f, 0.25f);
        float* tt = zc; zc = zn; zn = tt;
    }
    // W = attn2_inv @ kv   [256x256 @ 256x64]
    k_bmm_affine<<<dim3(1, 4, NBH), 256, 0, stream>>>(zc, kv, W, 256, 64, 256, 0.f, 1.f, 1.f);

    k_attn1_out<<<dim3(256, NBH), 256, 0, stream>>>(q, kl, W, v, cw, out);
}

// Round 4
// 941.844 us; speedup vs baseline: 8.3749x; 1.0066x over previous
//
#include <hip/hip_runtime.h>

// ---------------------------------------------------------------------------
// Nystrom attention, fp32. b=2,h=8,n=8192,d=64, m=256 landmarks, conv33.
// Round 4: 8x8-per-lane micro-tiles everywhere (LDS bytes/MAC 3->~1).
// ---------------------------------------------------------------------------

#define N_SEQ 8192
#define NBH   16
#define MLAND 256
#define DHEAD 64

// flash kernels' shared-memory layout (floats)
#define QT_STRIDE 264
#define QT_SIZE   (64 * QT_STRIDE)            // 16896 (Q transposed [k][m], 256 rows)
#define KP_OFF    QT_SIZE
#define KP_STRIDE 68
#define WC_OFF    (KP_OFF + 64 * KP_STRIDE)   // 21248
#define SMEM_FLOATS (WC_OFF + 64 * KP_STRIDE) // 25600 floats = 100 KB

__device__ __forceinline__ void fma8(float (&o)[8], float p, const float4& a, const float4& b) {
    o[0] += p * a.x; o[1] += p * a.y; o[2] += p * a.z; o[3] += p * a.w;
    o[4] += p * b.x; o[5] += p * b.y; o[6] += p * b.z; o[7] += p * b.w;
}

// ---------------------------------------------------------------------------
// 1) landmark means
// ---------------------------------------------------------------------------
__global__ __launch_bounds__(64) void k_landmarks(
    const float* __restrict__ q, const float* __restrict__ k,
    float* __restrict__ ql, float* __restrict__ kl)
{
    int mi = blockIdx.x & 255;
    int bh = blockIdx.x >> 8;
    const float* src = blockIdx.y ? k : q;
    float*       dst = blockIdx.y ? kl : ql;
    int t = threadIdx.x;
    const float* s = src + ((size_t)bh * N_SEQ + (size_t)mi * 32) * DHEAD;
    float acc = 0.f;
    #pragma unroll
    for (int j = 0; j < 32; ++j) acc += s[j * DHEAD + t];
    dst[((size_t)bh * MLAND + mi) * DHEAD + t] = acc * (1.f / 32.f);
}

// ---------------------------------------------------------------------------
// 2) attn2 = softmax(ql @ kl^T) rowwise
// ---------------------------------------------------------------------------
__global__ __launch_bounds__(256) void k_sim2_softmax(
    const float* __restrict__ ql, const float* __restrict__ kl,
    float* __restrict__ attn2)
{
    int bh = blockIdx.x >> 8;
    int i  = blockIdx.x & 255;
    int t  = threadIdx.x;
    __shared__ float qrow[DHEAD];
    __shared__ float wred[8];
    if (t < DHEAD) qrow[t] = ql[((size_t)bh * MLAND + i) * DHEAD + t];
    __syncthreads();
    const float* krow = kl + ((size_t)bh * MLAND + t) * DHEAD;
    float s = 0.f;
    #pragma unroll
    for (int kk = 0; kk < DHEAD; kk += 4) {
        float4 k4 = *(const float4*)(krow + kk);
        s += qrow[kk] * k4.x + qrow[kk + 1] * k4.y + qrow[kk + 2] * k4.z + qrow[kk + 3] * k4.w;
    }
    float m = s;
    #pragma unroll
    for (int o = 32; o > 0; o >>= 1) m = fmaxf(m, __shfl_xor(m, o, 64));
    int wave = t >> 6, lane = t & 63;
    if (lane == 0) wred[wave] = m;
    __syncthreads();
    float bm = fmaxf(fmaxf(wred[0], wred[1]), fmaxf(wred[2], wred[3]));
    float e = __expf(s - bm);
    float sum = e;
    #pragma unroll
    for (int o = 32; o > 0; o >>= 1) sum += __shfl_xor(sum, o, 64);
    if (lane == 0) wred[4 + wave] = sum;
    __syncthreads();
    float bs = wred[4] + wred[5] + wred[6] + wred[7];
    attn2[((size_t)bh * MLAND + i) * MLAND + t] = e / bs;
}

// ---------------------------------------------------------------------------
// 3a) global max of row-sums and col-sums of attn2
// ---------------------------------------------------------------------------
__global__ __launch_bounds__(256) void k_scale_reduce(
    const float* __restrict__ x, float* __restrict__ scl)
{
    int bh = blockIdx.x, t = threadIdx.x;
    const float* xb = x + (size_t)bh * MLAND * MLAND;
    float colsum = 0.f, rowsum = 0.f;
    for (int i = 0; i < MLAND; ++i) colsum += xb[(size_t)i * MLAND + t];
    for (int j = 0; j < MLAND; ++j) rowsum += xb[(size_t)t * MLAND + j];
    __shared__ float red[256];
    red[t] = rowsum;
    __syncthreads();
    for (int o = 128; o > 0; o >>= 1) {
        if (t < o) red[t] = fmaxf(red[t], red[t + o]);
        __syncthreads();
    }
    if (t == 0) atomicMax((unsigned int*)&scl[0], __float_as_uint(red[0]));
    __syncthreads();
    red[t] = colsum;
    __syncthreads();
    for (int o = 128; o > 0; o >>= 1) {
        if (t < o) red[t] = fmaxf(red[t], red[t + o]);
        __syncthreads();
    }
    if (t == 0) atomicMax((unsigned int*)&scl[1], __float_as_uint(red[0]));
}

// ---------------------------------------------------------------------------
// 3b) z0 = attn2^T / (scl[0]*scl[1])
// ---------------------------------------------------------------------------
__global__ __launch_bounds__(256) void k_zinit(
    const float* __restrict__ x, float* __restrict__ z,
    const float* __restrict__ scl)
{
    __shared__ float tile[32][33];
    int bh = blockIdx.z;
    int i0 = blockIdx.y * 32, j0 = blockIdx.x * 32;
    int t = threadIdx.x;
    int lx = t & 31, ly = t >> 5;
    const float* xb = x + (size_t)bh * MLAND * MLAND;
    float*       zb = z + (size_t)bh * MLAND * MLAND;
    #pragma unroll
    for (int p = 0; p < 4; ++p)
        tile[ly + 8 * p][lx] = xb[(size_t)(i0 + ly + 8 * p) * MLAND + j0 + lx];
    __syncthreads();
    float inv = 1.0f / (scl[0] * scl[1]);
    #pragma unroll
    for (int p = 0; p < 4; ++p)
        zb[(size_t)(j0 + ly + 8 * p) * MLAND + i0 + lx] = tile[lx][ly + 8 * p] * inv;
}

// ---------------------------------------------------------------------------
// 4) batched C = outscale * (A @ (diag*I + bscale*B)).
//    64x64 tile, 4 waves each own a K-quarter, 8x8 acc/lane, LDS reduce.
// ---------------------------------------------------------------------------
__global__ __launch_bounds__(256, 3) void k_bmm_affine(
    const float* __restrict__ A, const float* __restrict__ B, float* __restrict__ C,
    int M, int N, int K, float diag, float bscale, float outscale)
{
    __shared__ __align__(16) float sm[2 * 64 * 68];   // As | Bs; red reuses As
    int bh = blockIdx.z;
    const float* Ab = A + (size_t)bh * M * K;
    const float* Bb = B + (size_t)bh * K * N;
    float*       Cb = C + (size_t)bh * M * N;
    int m0 = blockIdx.y * 64, n0 = blockIdx.x * 64;
    int t = threadIdx.x;
    int wave = t >> 6, lane = t & 63;
    int ly = lane >> 3, lx = lane & 7;

    float acc[8][8] = {};
    for (int kc = 0; kc < K; kc += 64) {
        __syncthreads();
        {   // As[kk][m] (transposed)
            int m = t & 63, kq = t >> 6;
            const float* src = Ab + (size_t)(m0 + m) * K + kc + kq * 16;
            #pragma unroll
            for (int o = 0; o < 16; o += 4) {
                float4 a = *(const float4*)(src + o);
                sm[(kq * 16 + o + 0) * 68 + m] = a.x;
                sm[(kq * 16 + o + 1) * 68 + m] = a.y;
                sm[(kq * 16 + o + 2) * 68 + m] = a.z;
                sm[(kq * 16 + o + 3) * 68 + m] = a.w;
            }
        }
        {   // Bs[kk][n] with fused affine
            int kk = t & 63, nq = t >> 6;
            int gk = kc + kk;
            const float* src = Bb + (size_t)gk * N + n0 + nq * 16;
            #pragma unroll
            for (int o = 0; o < 16; o += 4) {
                float4 b = *(const float4*)(src + o);
                float r[4] = {b.x, b.y, b.z, b.w};
                #pragma unroll
                for (int u = 0; u < 4; ++u) {
                    float val = bscale * r[u];
                    if (gk == n0 + nq * 16 + o + u) val += diag;
                    r[u] = val;
                }
                *(float4*)&sm[64 * 68 + kk * 68 + nq * 16 + o] =
                    make_float4(r[0], r[1], r[2], r[3]);
            }
        }
        __syncthreads();
        #pragma unroll 2
        for (int k16 = 0; k16 < 16; ++k16) {
            int kk = wave * 16 + k16;
            float4 a0 = *(const float4*)&sm[kk * 68 + ly * 8];
            float4 a1 = *(const float4*)&sm[kk * 68 + ly * 8 + 4];
            float4 b0 = *(const float4*)&sm[64 * 68 + kk * 68 + lx * 8];
            float4 b1 = *(const float4*)&sm[64 * 68 + kk * 68 + lx * 8 + 4];
            float av[8] = {a0.x, a0.y, a0.z, a0.w, a1.x, a1.y, a1.z, a1.w};
            #pragma unroll
            for (int i = 0; i < 8; ++i) fma8(acc[i], av[i], b0, b1);
        }
    }
    // reduce waves 1..3 into wave 0 via LDS (As region, dead now)
    for (int w = 1; w < 4; ++w) {
        __syncthreads();
        if (wave == w) {
            #pragma unroll
            for (int i = 0; i < 8; ++i) {
                *(float4*)&sm[(ly * 8 + i) * 68 + lx * 8] =
                    make_float4(acc[i][0], acc[i][1], acc[i][2], acc[i][3]);
                *(float4*)&sm[(ly * 8 + i) * 68 + lx * 8 + 4] =
                    make_float4(acc[i][4], acc[i][5], acc[i][6], acc[i][7]);
            }
        }
        __syncthreads();
        if (wave == 0) {
            #pragma unroll
            for (int i = 0; i < 8; ++i) {
                float4 r0 = *(const float4*)&sm[(ly * 8 + i) * 68 + lx * 8];
                float4 r1 = *(const float4*)&sm[(ly * 8 + i) * 68 + lx * 8 + 4];
                acc[i][0] += r0.x; acc[i][1] += r0.y; acc[i][2] += r0.z; acc[i][3] += r0.w;
                acc[i][4] += r1.x; acc[i][5] += r1.y; acc[i][6] += r1.z; acc[i][7] += r1.w;
            }
        }
    }
    if (wave == 0) {
        #pragma unroll
        for (int i = 0; i < 8; ++i) {
            float* dst = Cb + (size_t)(m0 + ly * 8 + i) * N + n0 + lx * 8;
            *(float4*)dst = make_float4(acc[i][0] * outscale, acc[i][1] * outscale,
                                        acc[i][2] * outscale, acc[i][3] * outscale);
            *(float4*)(dst + 4) = make_float4(acc[i][4] * outscale, acc[i][5] * outscale,
                                              acc[i][6] * outscale, acc[i][7] * outscale);
        }
    }
}

// ---------------------------------------------------------------------------
// 5a) attn3 flash partial: all 256 landmarks per block, 512-key split.
//     grid (16 splits, NBH), block 256 (4 waves x (ly,lx)=8x8), 8x8/lane.
// ---------------------------------------------------------------------------
__global__ __launch_bounds__(256, 1) void k_attn3_partial(
    const float* __restrict__ ql, const float* __restrict__ k,
    const float* __restrict__ v, float* __restrict__ pO,
    float* __restrict__ pm, float* __restrict__ pl)
{
    __shared__ __align__(16) float smem[SMEM_FLOATS];
    int sp = blockIdx.x;
    int bh = blockIdx.y;
    int t = threadIdx.x;
    int wave = t >> 6, lane = t & 63;
    int ly = lane >> 3, lx = lane & 7;
    int rbase = wave * 64 + ly * 8;   // landmark row base for this lane

    {   // stage all 256 landmark q-rows transposed: qs_t[k][m]
        const float* src = ql + ((size_t)bh * MLAND + t) * DHEAD;
        #pragma unroll
        for (int kk = 0; kk < DHEAD; kk += 4) {
            float4 a = *(const float4*)(src + kk);
            smem[(kk + 0) * QT_STRIDE + t] = a.x;
            smem[(kk + 1) * QT_STRIDE + t] = a.y;
            smem[(kk + 2) * QT_STRIDE + t] = a.z;
            smem[(kk + 3) * QT_STRIDE + t] = a.w;
        }
    }

    float S[8][8], O[8][8] = {};
    float M[8], L[8];
    #pragma unroll
    for (int i = 0; i < 8; ++i) { M[i] = -1e30f; L[i] = 0.f; }

    const float* kb = k + (size_t)bh * N_SEQ * DHEAD;
    const float* vb = v + (size_t)bh * N_SEQ * DHEAD;

    for (int cc = 0; cc < 8; ++cc) {
        int c0 = sp * 512 + cc * 64;
        __syncthreads();
        {   // kp = K^T chunk [kk][j]
            int j = t & 63, kq = t >> 6;
            const float* src = kb + (size_t)(c0 + j) * DHEAD + kq * 16;
            #pragma unroll
            for (int o = 0; o < 16; o += 4) {
                float4 a = *(const float4*)(src + o);
                smem[KP_OFF + (kq * 16 + o + 0) * KP_STRIDE + j] = a.x;
                smem[KP_OFF + (kq * 16 + o + 1) * KP_STRIDE + j] = a.y;
                smem[KP_OFF + (kq * 16 + o + 2) * KP_STRIDE + j] = a.z;
                smem[KP_OFF + (kq * 16 + o + 3) * KP_STRIDE + j] = a.w;
            }
        }
        {   // wc = V chunk natural [j][d]
            int j = t & 63, dq = t >> 6;
            const float* src = vb + (size_t)(c0 + j) * DHEAD + dq * 16;
            #pragma unroll
            for (int o = 0; o < 16; o += 4)
                *(float4*)&smem[WC_OFF + j * KP_STRIDE + dq * 16 + o] =
                    *(const float4*)(src + o);
        }
        __syncthreads();

        // S = Q @ K^T
        #pragma unroll
        for (int i = 0; i < 8; ++i)
            #pragma unroll
            for (int j = 0; j < 8; ++j) S[i][j] = 0.f;
        #pragma unroll 4
        for (int kk = 0; kk < DHEAD; ++kk) {
            float4 a0 = *(const float4*)&smem[kk * QT_STRIDE + rbase];
            float4 a1 = *(const float4*)&smem[kk * QT_STRIDE + rbase + 4];
            float4 b0 = *(const float4*)&smem[KP_OFF + kk * KP_STRIDE + lx * 8];
            float4 b1 = *(const float4*)&smem[KP_OFF + kk * KP_STRIDE + lx * 8 + 4];
            float av[8] = {a0.x, a0.y, a0.z, a0.w, a1.x, a1.y, a1.z, a1.w};
            #pragma unroll
            for (int i = 0; i < 8; ++i) fma8(S[i], av[i], b0, b1);
        }

        // online softmax (8 lx lanes share each row)
        #pragma unroll
        for (int i = 0; i < 8; ++i) {
            float mv = S[i][0];
            #pragma unroll
            for (int j = 1; j < 8; ++j) mv = fmaxf(mv, S[i][j]);
            mv = fmaxf(mv, __shfl_xor(mv, 4, 8));
            mv = fmaxf(mv, __shfl_xor(mv, 2, 8));
            mv = fmaxf(mv, __shfl_xor(mv, 1, 8));
            float nM = fmaxf(M[i], mv);
            float alpha = __expf(M[i] - nM);
            M[i] = nM;
            float rs = 0.f;
            #pragma unroll
            for (int j = 0; j < 8; ++j) { S[i][j] = __expf(S[i][j] - nM); rs += S[i][j]; }
            rs += __shfl_xor(rs, 4, 8);
            rs += __shfl_xor(rs, 2, 8);
            rs += __shfl_xor(rs, 1, 8);
            L[i] = L[i] * alpha + rs;
            #pragma unroll
            for (int j = 0; j < 8; ++j) O[i][j] *= alpha;
        }

        // O += P @ V (P stays in registers; broadcast via width-8 shuffles)
        #pragma unroll 2
        for (int lsrc = 0; lsrc < 8; ++lsrc) {
            #pragma unroll
            for (int jq = 0; jq < 8; ++jq) {
                int j = lsrc * 8 + jq;
                float4 v0 = *(const float4*)&smem[WC_OFF + j * KP_STRIDE + lx * 8];
                float4 v1 = *(const float4*)&smem[WC_OFF + j * KP_STRIDE + lx * 8 + 4];
                #pragma unroll
                for (int i = 0; i < 8; ++i) {
                    float p = __shfl(S[i][jq], lsrc, 8);
                    fma8(O[i], p, v0, v1);
                }
            }
        }
    }

    int base = (bh * 16 + sp) * MLAND;
    #pragma unroll
    for (int i = 0; i < 8; ++i) {
        int r = rbase + i;
        if (lx == 0) { pm[base + r] = M[i]; pl[base + r] = L[i]; }
        float* dst = pO + (size_t)(base + r) * DHEAD + lx * 8;
        *(float4*)dst = make_float4(O[i][0], O[i][1], O[i][2], O[i][3]);
        *(float4*)(dst + 4) = make_float4(O[i][4], O[i][5], O[i][6], O[i][7]);
    }
}

// ---------------------------------------------------------------------------
// 5b) combine 16 splits -> kv
// ---------------------------------------------------------------------------
__global__ __launch_bounds__(64) void k_attn3_combine(
    const float* __restrict__ pO, const float* __restrict__ pm,
    const float* __restrict__ pl, float* __restrict__ kv)
{
    int bh = blockIdx.x >> 8;
    int m  = blockIdx.x & 255;
    int d  = threadIdx.x;
    float M = -1e30f;
    #pragma unroll
    for (int s = 0; s < 16; ++s) M = fmaxf(M, pm[(bh * 16 + s) * MLAND + m]);
    float L = 0.f, O = 0.f;
    #pragma unroll
    for (int s = 0; s < 16; ++s) {
        int base = (bh * 16 + s) * MLAND + m;
        float w = __expf(pm[base] - M);
        L += pl[base] * w;
        O += w * pO[(size_t)base * DHEAD + d];
    }
    kv[((size_t)bh * MLAND + m) * DHEAD + d] = O / L;
}

// ---------------------------------------------------------------------------
// 6) out = softmax(q @ kl^T) @ W + conv33(v). 256 q-rows/block, 8x8/lane.
//    grid (32, NBH), block 256.
// ---------------------------------------------------------------------------
__global__ __launch_bounds__(256, 1) void k_attn1_out(
    const float* __restrict__ q, const float* __restrict__ kl,
    const float* __restrict__ W, const float* __restrict__ v,
    const float* __restrict__ cw, float* __restrict__ out)
{
    __shared__ __align__(16) float smem[SMEM_FLOATS];
    __shared__ float wgt[33];
    int bh = blockIdx.y;
    int r0 = blockIdx.x * 256;
    int t = threadIdx.x;
    int wave = t >> 6, lane = t & 63;
    int ly = lane >> 3, lx = lane & 7;
    int rbase = wave * 64 + ly * 8;

    if (t < 33) wgt[t] = cw[(bh & 7) * 33 + t];
    {   // stage 256 q-rows transposed
        const float* src = q + ((size_t)bh * N_SEQ + r0 + t) * DHEAD;
        #pragma unroll
        for (int kk = 0; kk < DHEAD; kk += 4) {
            float4 a = *(const float4*)(src + kk);
            smem[(kk + 0) * QT_STRIDE + t] = a.x;
            smem[(kk + 1) * QT_STRIDE + t] = a.y;
            smem[(kk + 2) * QT_STRIDE + t] = a.z;
            smem[(kk + 3) * QT_STRIDE + t] = a.w;
        }
    }

    float S[8][8], O[8][8] = {};
    float M[8], L[8];
    #pragma unroll
    for (int i = 0; i < 8; ++i) { M[i] = -1e30f; L[i] = 0.f; }

    for (int mc = 0; mc < 4; ++mc) {
        __syncthreads();
        {   // kp = kl^T chunk
            int j = t & 63, kq = t >> 6;
            const float* src = kl + ((size_t)bh * MLAND + mc * 64 + j) * DHEAD + kq * 16;
            #pragma unroll
            for (int o = 0; o < 16; o += 4) {
                float4 a = *(const float4*)(src + o);
                smem[KP_OFF + (kq * 16 + o + 0) * KP_STRIDE + j] = a.x;
                smem[KP_OFF + (kq * 16 + o + 1) * KP_STRIDE + j] = a.y;
                smem[KP_OFF + (kq * 16 + o + 2) * KP_STRIDE + j] = a.z;
                smem[KP_OFF + (kq * 16 + o + 3) * KP_STRIDE + j] = a.w;
            }
        }
        {   // wc = W chunk natural
            int j = t & 63, dq = t >> 6;
            const float* src = W + ((size_t)bh * MLAND + mc * 64 + j) * DHEAD + dq * 16;
            #pragma unroll
            for (int o = 0; o < 16; o += 4)
                *(float4*)&smem[WC_OFF + j * KP_STRIDE + dq * 16 + o] =
                    *(const float4*)(src + o);
        }
        __syncthreads();

        #pragma unroll
        for (int i = 0; i < 8; ++i)
            #pragma unroll
            for (int j = 0; j < 8; ++j) S[i][j] = 0.f;
        #pragma unroll 4
        for (int kk = 0; kk < DHEAD; ++kk) {
            float4 a0 = *(const float4*)&smem[kk * QT_STRIDE + rbase];
            float4 a1 = *(const float4*)&smem[kk * QT_STRIDE + rbase + 4];
            float4 b0 = *(const float4*)&smem[KP_OFF + kk * KP_STRIDE + lx * 8];
            float4 b1 = *(const float4*)&smem[KP_OFF + kk * KP_STRIDE + lx * 8 + 4];
            float av[8] = {a0.x, a0.y, a0.z, a0.w, a1.x, a1.y, a1.z, a1.w};
            #pragma unroll
            for (int i = 0; i < 8; ++i) fma8(S[i], av[i], b0, b1);
        }

        #pragma unroll
        for (int i = 0; i < 8; ++i) {
            float mv = S[i][0];
            #pragma unroll
            for (int j = 1; j < 8; ++j) mv = fmaxf(mv, S[i][j]);
            mv = fmaxf(mv, __shfl_xor(mv, 4, 8));
            mv = fmaxf(mv, __shfl_xor(mv, 2, 8));
            mv = fmaxf(mv, __shfl_xor(mv, 1, 8));
            float nM = fmaxf(M[i], mv);
            float alpha = __expf(M[i] - nM);
            M[i] = nM;
            float rs = 0.f;
            #pragma unroll
            for (int j = 0; j < 8; ++j) { S[i][j] = __expf(S[i][j] - nM); rs += S[i][j]; }
            rs += __shfl_xor(rs, 4, 8);
            rs += __shfl_xor(rs, 2, 8);
            rs += __shfl_xor(rs, 1, 8);
            L[i] = L[i] * alpha + rs;
            #pragma unroll
            for (int j = 0; j < 8; ++j) O[i][j] *= alpha;
        }

        #pragma unroll 2
        for (int lsrc = 0; lsrc < 8; ++lsrc) {
            #pragma unroll
            for (int jq = 0; jq < 8; ++jq) {
                int j = lsrc * 8 + jq;
                float4 v0 = *(const float4*)&smem[WC_OFF + j * KP_STRIDE + lx * 8];
                float4 v1 = *(const float4*)&smem[WC_OFF + j * KP_STRIDE + lx * 8 + 4];
                #pragma unroll
                for (int i = 0; i < 8; ++i) {
                    float p = __shfl(S[i][jq], lsrc, 8);
                    fma8(O[i], p, v0, v1);
                }
            }
        }
    }

    float inv[8];
    #pragma unroll
    for (int i = 0; i < 8; ++i) inv[i] = 1.0f / L[i];

    // conv: stage v rows [r0-16, r0+272) into smem (stride 68)
    __syncthreads();
    for (int rr = t; rr < 288; rr += 256) {
        int gr = r0 - 16 + rr;
        bool ok = (gr >= 0) && (gr < N_SEQ);
        const float* src = v + ((size_t)bh * N_SEQ + gr) * DHEAD;
        #pragma unroll
        for (int c = 0; c < 64; c += 4) {
            float4 val = ok ? *(const float4*)(src + c) : make_float4(0.f, 0.f, 0.f, 0.f);
            *(float4*)&smem[rr * 68 + c] = val;
        }
    }
    __syncthreads();

    float res[8][8] = {};
    #pragma unroll
    for (int w = 0; w < 40; ++w) {
        float4 va = *(const float4*)&smem[(rbase + w) * 68 + lx * 8];
        float4 vb4 = *(const float4*)&smem[(rbase + w) * 68 + lx * 8 + 4];
        #pragma unroll
        for (int i = 0; i < 8; ++i) {
            if (w - i >= 0 && w - i <= 32) {
                float wv = wgt[w - i];
                fma8(res[i], wv, va, vb4);
            }
        }
    }

    #pragma unroll
    for (int i = 0; i < 8; ++i) {
        float* dst = out + ((size_t)bh * N_SEQ + r0 + rbase + i) * DHEAD + lx * 8;
        *(float4*)dst = make_float4(O[i][0] * inv[i] + res[i][0], O[i][1] * inv[i] + res[i][1],
                                    O[i][2] * inv[i] + res[i][2], O[i][3] * inv[i] + res[i][3]);
        *(float4*)(dst + 4) = make_float4(O[i][4] * inv[i] + res[i][4], O[i][5] * inv[i] + res[i][5],
                                          O[i][6] * inv[i] + res[i][6], O[i][7] * inv[i] + res[i][7]);
    }
}

// ---------------------------------------------------------------------------
// launch
// ---------------------------------------------------------------------------
extern "C" void kernel_launch(void* const* d_in, const int* in_sizes, int n_in,
                              void* d_out, int out_size, void* d_ws, size_t ws_size,
                              hipStream_t stream)
{
    (void)in_sizes; (void)n_in; (void)out_size; (void)ws_size;
    const float* q  = (const float*)d_in[0];
    const float* k  = (const float*)d_in[1];
    const float* v  = (const float*)d_in[2];
    const float* cw = (const float*)d_in[3];
    float* out = (float*)d_out;
    float* ws  = (float*)d_ws;

    const size_t LM = (size_t)NBH * MLAND * DHEAD;   // 262144 floats
    const size_t MM = (size_t)NBH * MLAND * MLAND;   // 1048576 floats
    float* ql  = ws;
    float* kl  = ql  + LM;
    float* x   = kl  + LM;   // attn2
    float* z   = x   + MM;
    float* z2  = z   + MM;
    float* xz  = z2  + MM;
    float* t2  = xz  + MM;
    float* t3  = t2  + MM;
    float* kv  = t3  + MM;
    float* W   = kv  + LM;
    float* scl = W   + LM;   // 16 floats (2 used)
    float* pm  = scl + 16;               // 16*16*256 = 65536
    float* pl  = pm + (size_t)NBH * 16 * MLAND;

    // attn3 partials: pO spans z2..t3 (exactly 4*MM floats), dead before pinv.
    float* pO = z2;

    hipMemsetAsync(scl, 0, 2 * sizeof(float), stream);

    k_landmarks<<<dim3(NBH * MLAND, 2), 64, 0, stream>>>(q, k, ql, kl);
    k_sim2_softmax<<<NBH * MLAND, 256, 0, stream>>>(ql, kl, x);
    k_scale_reduce<<<NBH, 256, 0, stream>>>(x, scl);
    k_zinit<<<dim3(8, 8, NBH), 256, 0, stream>>>(x, z, scl);

    k_attn3_partial<<<dim3(16, NBH), 256, 0, stream>>>(ql, k, v, pO, pm, pl);
    k_attn3_combine<<<NBH * MLAND, 64, 0, stream>>>(pO, pm, pl, kv);

    // Moore-Penrose: z' = 0.25*z@(13I - xz@(15I - xz@(7I - xz))), xz = x@z
    float* zc = z;
    float* zn = z2;
    for (int it = 0; it < 6; ++it) {
        k_bmm_affine<<<dim3(4, 4, NBH), 256, 0, stream>>>(x,  zc, xz, 256, 256, 256,  0.f,  1.f, 1.f);
        k_bmm_affine<<<dim3(4, 4, NBH), 256, 0, stream>>>(xz, xz, t2, 256, 256, 256,  7.f, -1.f, 1.f);
        k_bmm_affine<<<dim3(4, 4, NBH), 256, 0, stream>>>(xz, t2, t3, 256, 256, 256, 15.f, -1.f, 1.f);
        k_bmm_affine<<<dim3(4, 4, NBH), 256, 0, stream>>>(zc, t3, zn, 256, 256, 256, 13.f, -1.f, 0.25f);
        float* tt = zc; zc = zn; zn = tt;
    }
    // W = attn2_inv @ kv   [256x256 @ 256x64]
    k_bmm_affine<<<dim3(1, 4, NBH), 256, 0, stream>>>(zc, kv, W, 256, 64, 256, 0.f, 1.f, 1.f);

    k_attn1_out<<<dim3(32, NBH), 256, 0, stream>>>(q, kl, W, v, cw, out);
}